// Round 17
// baseline (218.714 us; speedup 1.0000x reference)
//
#include <hip/hip_runtime.h>
#include <hip/hip_bf16.h>

typedef __bf16 bf16;
typedef __attribute__((ext_vector_type(8))) __bf16 bf16x8;
typedef __attribute__((ext_vector_type(4))) __bf16 bf16x4;
typedef __attribute__((ext_vector_type(4))) float f32x4;
typedef __attribute__((ext_vector_type(16))) float f32x16;
typedef __attribute__((ext_vector_type(4))) unsigned int u32x4;

#define MFMA16(a, b, c) __builtin_amdgcn_mfma_f32_16x16x32_bf16((a), (b), (c), 0, 0, 0)
#define MFMA32(a, b, c) __builtin_amdgcn_mfma_f32_32x32x16_bf16((a), (b), (c), 0, 0, 0)

constexpr int Bn = 2, Tn = 2048, Cn = 1024, Hn = 16, Dn = 64;
constexpr int Mn = Bn * Tn;
constexpr int WSZ = Cn * Cn;
constexpr int XSZ = Mn * Cn;
constexpr float LOG2E = 1.44269504088896f;

// async global->LDS, 16B/lane: LDS dest = wave-uniform base + lane*16
__device__ __forceinline__ void async_cp16(bf16* lds, const bf16* g) {
  __builtin_amdgcn_global_load_lds(
      (const __attribute__((address_space(1))) unsigned int*)g,
      (__attribute__((address_space(3))) unsigned int*)lds, 16, 0, 0);
}

__device__ __forceinline__ unsigned int cvtpk(float lo, float hi) {
  unsigned int r;
  asm("v_cvt_pk_bf16_f32 %0, %1, %2" : "=v"(r) : "v"(lo), "v"(hi));
  return r;
}

struct GemmArgs {
  const bf16* A[3];
  const bf16* Bt[3];
  const float* bias[3];
  void* out[3];
  float scale[3];
  int layout[3];   // 0 = fp32 [M,N]; 1 = bf16 [B,H,T,D]; 2 = bf16 [B,H,D,T]
};

struct PrepArgs {
  const float* W[4];
  bf16* Wt[4];
  const float* src[3];
  bf16* dst;
};

// ---------------- fused prep: activations fp32->bf16 + W transpose ----------------
__global__ __launch_bounds__(256) void prep_kernel(PrepArgs pa) {
  __shared__ float tile[32][33];
  const int id = blockIdx.x;
  const int tid = threadIdx.x;
  if (id < 6144) {
    const int z = id >> 11;
    const float* __restrict__ s = pa.src[z];
    size_t idx = ((size_t)(id & 2047) * 256 + tid) * 8;
    float4 a = *(const float4*)&s[idx];
    float4 b = *(const float4*)&s[idx + 4];
    bf16x8 o = {(bf16)a.x, (bf16)a.y, (bf16)a.z, (bf16)a.w,
                (bf16)b.x, (bf16)b.y, (bf16)b.z, (bf16)b.w};
    *(bf16x8*)&pa.dst[(size_t)z * XSZ + idx] = o;
  } else {
    const int t = id - 6144;        // 0..4095
    const int z = t >> 10;
    const int rem = t & 1023;
    const int bxp = rem & 31, byp = rem >> 5;
    const float* __restrict__ W = pa.W[z];
    bf16* __restrict__ Wt = pa.Wt[z];
    const int tx = tid & 31, ty = tid >> 5;   // (32,8)
    const int x = bxp * 32 + tx;
    const int y0 = byp * 32;
    for (int j = 0; j < 32; j += 8) tile[ty + j][tx] = W[(y0 + ty + j) * Cn + x];
    __syncthreads();
    const int n0 = bxp * 32;
    const int k = byp * 32 + tx;
    for (int j = 0; j < 32; j += 8)
      Wt[(n0 + ty + j) * Cn + k] = (bf16)tile[tx][ty + j];
  }
}

// ---------------- GEMM: C[M,N] = A[M,K] @ Wt[N,K]^T + bias ----------------
// BM x 128 tile, BK=64, async 16B staging, XOR chunk swizzle.
// v14 (kept): y-chunked XCD swizzle (T1) — FETCH 101MB->37MB verified.
// v17 (kept): single-buffer 2-barrier. v18 (kept): QKV BM=64 (neutral-to-+).
template <int BM>
__global__ __launch_bounds__(256) void gemm_kernel(GemmArgs args, int K) {
  constexpr int MT = BM / 32;          // m-tiles per wave
  const int z = blockIdx.z;
  const bf16* __restrict__ A = args.A[z];
  const bf16* __restrict__ Bt = args.Bt[z];
  const float* __restrict__ bias = args.bias[z];
  const float scale = args.scale[z];
  const int layout = args.layout[z];

  __shared__ bf16 As[BM * 64];
  __shared__ bf16 Bs[128 * 64];

  const int tid = threadIdx.x;
  const int w = tid >> 6, lane = tid & 63;
  const int wm = w >> 1, wn = w & 1;
  const int g = lane >> 4, l15 = lane & 15;
  const int r8 = lane >> 3, c8 = lane & 7;
  const int soff = (c8 ^ r8) << 3;
  const int kk = l15 & 7;
  const int off0 = (g ^ kk) << 3;
  const int off1 = ((4 + g) ^ kk) << 3;

  // y-chunked XCD swizzle
  const int nx = gridDim.x;
  const int nwg = nx * gridDim.y;
  const int raw = blockIdx.x + nx * blockIdx.y;
  const int cpx = nwg >> 3;
  const int logical = (raw & 7) * cpx + (raw >> 3);
  const int bx = logical % nx, by = logical / nx;
  const int m0 = by * BM, n0 = bx * 128;

  f32x4 acc[MT][4] = {};

  for (int k0 = 0; k0 < K; k0 += 64) {
    __syncthreads();
    for (int i = 0; i < BM / 32; i++) {
      int p = w * (BM / 32) + i;
      async_cp16(&As[p * 512], &A[(size_t)(m0 + p * 8 + r8) * K + k0 + soff]);
    }
    for (int i = 0; i < 4; i++) {
      int p = w * 4 + i;
      async_cp16(&Bs[p * 512], &Bt[(size_t)(n0 + p * 8 + r8) * K + k0 + soff]);
    }
    __syncthreads();

    for (int ks = 0; ks < 2; ks++) {
      const int off = ks ? off1 : off0;
      bf16x8 af[MT], bfr[4];
      for (int mt = 0; mt < MT; mt++)
        af[mt] = *(const bf16x8*)&As[(wm * (BM / 2) + mt * 16 + l15) * 64 + off];
      for (int nt = 0; nt < 4; nt++)
        bfr[nt] = *(const bf16x8*)&Bs[(wn * 64 + nt * 16 + l15) * 64 + off];
      for (int mt = 0; mt < MT; mt++)
        for (int nt = 0; nt < 4; nt++)
          acc[mt][nt] = MFMA16(af[mt], bfr[nt], acc[mt][nt]);
    }
  }

  // epilogue: C/D layout row=(lane>>4)*4+r, col=lane&15
  for (int mt = 0; mt < MT; mt++) {
    for (int nt = 0; nt < 4; nt++) {
      int gn = n0 + wn * 64 + nt * 16 + l15;
      float bb = bias[gn];
      int gm0 = m0 + wm * (BM / 2) + mt * 16 + g * 4;
      float v[4];
      for (int r = 0; r < 4; r++) v[r] = (acc[mt][nt][r] + bb) * scale;
      if (layout == 2) {
        // V^T: bf16 [B,H,D,T]; r -> consecutive t
        int b = gm0 >> 11, t = gm0 & 2047, h = gn >> 6, d = gn & 63;
        bf16x4 ov = {(bf16)v[0], (bf16)v[1], (bf16)v[2], (bf16)v[3]};
        *(bf16x4*)&((bf16*)args.out[z])[(size_t)((b * Hn + h) * Dn + d) * Tn + t] = ov;
      } else if (layout == 1) {
        int b = gm0 >> 11, t = gm0 & 2047, h = gn >> 6, d = gn & 63;
        bf16* o = (bf16*)args.out[z] + (size_t)((b * Hn + h) * Tn + t) * Dn + d;
        for (int r = 0; r < 4; r++) o[(size_t)r * Dn] = (bf16)v[r];
      } else {
        float* o = (float*)args.out[z] + (size_t)gm0 * Cn + gn;
        for (int r = 0; r < 4; r++) o[(size_t)r * Cn] = v[r];
      }
    }
  }
}

// ---------------- Flash attention v19 ----------------
// LDS-traffic model of the 47us wall: each wave re-reads the full K/V tile
// (8KB/iter) for only 32 q-rows -> 32 FLOP/B vs LDS; 2.1GB total = ~45TB/s
// ~60% of LDS ceiling + conflicts + staging. Occupancy-invariant (v10/12/13).
// v19: DOUBLE PER-WAVE Q-TILING (32 -> 64 q-rows/wave). Each K/V frag read
// now feeds 2 q-subtiles' MFMAs -> LDS read traffic per FLOP HALVES.
// Same KVB=32, same swizzles, same kv-half split + in-block combine (4
// phases of <=17KB). Cost: VGPR ~190 -> ~2 waves/SIMD (immaterial per v13).
// Grid: 256 blocks x 512 thr (4 q-waves x 64 rows x 2 kv halves).
constexpr int KVB = 32;
constexpr int NTt = Tn / KVB;   // 64 kv tiles total; 32 per half

struct PvOn  { static constexpr bool value = true;  };
struct PvOff { static constexpr bool value = false; };

__global__ __launch_bounds__(512) void attn_kernel(const bf16* __restrict__ Qh,
                                                   const bf16* __restrict__ Kh,
                                                   const bf16* __restrict__ VhT,
                                                   bf16* __restrict__ AO) {
  __shared__ char smem[32768];   // per half (16KB): K[2][2048] | V[2][2048]; reused as combine buf

  const int tid = threadIdx.x;
  const int w = tid >> 6, lane = tid & 63;
  const int qw = w & 3, half = w >> 2;
  const int l31 = lane & 31, hi = lane >> 5;
  const int id = blockIdx.x;
  const int bh = id & 31;           // low bits -> same-bh blocks share an XCD
  const int q0 = (id >> 5) * 256;   // 8 q-tiles of 256 rows
  const int t0 = half * (NTt / 2);
  const int tend = t0 + NTt / 2;
  const size_t hb = (size_t)bh * Tn * Dn;
  const size_t hbT = (size_t)bh * Dn * Tn;
  // K staging: lane -> rel row r8 = lane>>3 (8 rows/wave), chunk c8 = lane&7
  const int r8 = lane >> 3, c8 = lane & 7;
  const int soff = (c8 ^ r8) << 3;              // K global chunk pre-swizzle
  // V staging: lane -> rel row rv = lane>>2 (16 rows/wave), chunk cv = lane&3
  const int rv = lane >> 2, cv = lane & 3;
  const int voff = ((cv ^ ((rv >> 1) & 3)) << 3);  // V pre-swizzle, f(row)=(row>>1)&3
  // K-frag read addressing: row r, chunk c at (r>>3)*512 + (r&7)*64 + ((c^(r&7))<<3)
  const int sw7 = l31 & 7;
  const int baseK = ((l31 >> 3) << 9) + (sw7 << 6);
  // V-frag read addressing: row r (=l31 / +32), chunk c at r*32 + ((c^((r>>1)&3))<<3)
  const int sw3 = (l31 >> 1) & 3;
  const int baseV = l31 << 5;

  bf16* Ks = (bf16*)(smem + half * 16384);            // [2][2048]
  bf16* Vt = (bf16*)(smem + half * 16384 + 8192);     // [2][2048]

  // Q fragments (B-operand) for TWO q-subtiles: qA = q0+qw*64+l31, qB = qA+32
  bf16x8 qfA[4], qfB[4];
  {
    const bf16* qpA = Qh + hb + (size_t)(q0 + qw * 64 + l31) * Dn + hi * 8;
    const bf16* qpB = qpA + (size_t)32 * Dn;
#pragma unroll
    for (int ks = 0; ks < 4; ks++) {
      qfA[ks] = *(const bf16x8*)(qpA + ks * 16);
      qfB[ks] = *(const bf16x8*)(qpB + ks * 16);
    }
  }

  f32x16 o0 = {}, o1 = {}, o2 = {}, o3 = {};   // [qsubA: o0/o1][qsubB: o2/o3]
  float lA = 0.f, lB = 0.f;
  bf16x8 vf0[2], vf1[2];    // V^T frags of tile t (d 0-31 / 32-63), shared by both qsubs
  bf16x8 pfvA[2], pfvB[2];  // P frags of tile t per qsub, consumed iter t+1

  // prologue: stage tile t0 into buffer 0 (2 loads/wave: 1 K + 1 V)
  async_cp16(&Ks[qw * 512], &Kh[hb + (size_t)(t0 * KVB + qw * 8 + r8) * Dn + soff]);
  async_cp16(&Vt[qw * 512], &VhT[hbT + (size_t)(qw * 16 + rv) * Tn + t0 * KVB + voff]);
  __syncthreads();

  auto body = [&](int kt, auto pvtag) {
    constexpr bool PV = decltype(pvtag)::value;
    const int cur = kt & 1;   // t0 is even for both halves
    if (kt + 1 < tend) {
      const int nxt = cur ^ 1;
      const int t1 = (kt + 1) * KVB;
      async_cp16(&Ks[nxt * 2048 + qw * 512], &Kh[hb + (size_t)(t1 + qw * 8 + r8) * Dn + soff]);
      async_cp16(&Vt[nxt * 2048 + qw * 512], &VhT[hbT + (size_t)(qw * 16 + rv) * Tn + t1 + voff]);
    }

    // S^T = K Q^T : 32 kv rows x 2 q-subtiles; ONE K-frag read feeds 2 MFMAs
    f32x16 sA = {}, sB = {};
    const bf16* ksb = &Ks[cur * 2048];
    __builtin_amdgcn_s_setprio(1);
#pragma unroll
    for (int ks = 0; ks < 4; ks++) {
      bf16x8 kf = *(const bf16x8*)(ksb + baseK + (((ks * 2 + hi) ^ sw7) << 3));
      sA = MFMA32(kf, qfA[ks], sA);
      sB = MFMA32(kf, qfB[ks], sB);
    }
    __builtin_amdgcn_s_setprio(0);

    // exp(t) interleaved with PV(t-1) for qsubA
    float peA[16], peB[16];
    float rA0 = 0.f, rA1 = 0.f, rB0 = 0.f, rB1 = 0.f;
#pragma unroll
    for (int gq = 0; gq < 4; gq++) {
      float e0 = __builtin_amdgcn_exp2f(sA[gq * 4 + 0]);
      float e1 = __builtin_amdgcn_exp2f(sA[gq * 4 + 1]);
      float e2 = __builtin_amdgcn_exp2f(sA[gq * 4 + 2]);
      float e3 = __builtin_amdgcn_exp2f(sA[gq * 4 + 3]);
      peA[gq * 4 + 0] = e0; peA[gq * 4 + 1] = e1;
      peA[gq * 4 + 2] = e2; peA[gq * 4 + 3] = e3;
      rA0 += e0 + e1; rA1 += e2 + e3;
      if constexpr (PV) {
        if (gq < 2) o0 = MFMA32(vf0[gq], pfvA[gq], o0);
        else        o1 = MFMA32(vf1[gq - 2], pfvA[gq - 2], o1);
      }
    }
    // exp(t) interleaved with PV(t-1) for qsubB
#pragma unroll
    for (int gq = 0; gq < 4; gq++) {
      float e0 = __builtin_amdgcn_exp2f(sB[gq * 4 + 0]);
      float e1 = __builtin_amdgcn_exp2f(sB[gq * 4 + 1]);
      float e2 = __builtin_amdgcn_exp2f(sB[gq * 4 + 2]);
      float e3 = __builtin_amdgcn_exp2f(sB[gq * 4 + 3]);
      peB[gq * 4 + 0] = e0; peB[gq * 4 + 1] = e1;
      peB[gq * 4 + 2] = e2; peB[gq * 4 + 3] = e3;
      rB0 += e0 + e1; rB1 += e2 + e3;
      if constexpr (PV) {
        if (gq < 2) o2 = MFMA32(vf0[gq], pfvB[gq], o2);
        else        o3 = MFMA32(vf1[gq - 2], pfvB[gq - 2], o3);
      }
    }
    lA += rA0 + rA1;
    lB += rB0 + rB1;

    // pack P in-register per qsub: pfv[0]=kv 0..15, pfv[1]=kv 16..31
    {
      unsigned a0 = cvtpk(peA[0], peA[1]),  a1 = cvtpk(peA[2], peA[3]);
      unsigned b0 = cvtpk(peA[4], peA[5]),  b1 = cvtpk(peA[6], peA[7]);
      auto s0 = __builtin_amdgcn_permlane32_swap(a0, b0, false, false);
      auto s1 = __builtin_amdgcn_permlane32_swap(a1, b1, false, false);
      u32x4 w0 = {s0[0], s1[0], s0[1], s1[1]};
      pfvA[0] = __builtin_bit_cast(bf16x8, w0);
      a0 = cvtpk(peA[8], peA[9]);   a1 = cvtpk(peA[10], peA[11]);
      b0 = cvtpk(peA[12], peA[13]); b1 = cvtpk(peA[14], peA[15]);
      s0 = __builtin_amdgcn_permlane32_swap(a0, b0, false, false);
      s1 = __builtin_amdgcn_permlane32_swap(a1, b1, false, false);
      u32x4 w1 = {s0[0], s1[0], s0[1], s1[1]};
      pfvA[1] = __builtin_bit_cast(bf16x8, w1);
      a0 = cvtpk(peB[0], peB[1]);   a1 = cvtpk(peB[2], peB[3]);
      b0 = cvtpk(peB[4], peB[5]);   b1 = cvtpk(peB[6], peB[7]);
      s0 = __builtin_amdgcn_permlane32_swap(a0, b0, false, false);
      s1 = __builtin_amdgcn_permlane32_swap(a1, b1, false, false);
      u32x4 w2 = {s0[0], s1[0], s0[1], s1[1]};
      pfvB[0] = __builtin_bit_cast(bf16x8, w2);
      a0 = cvtpk(peB[8], peB[9]);   a1 = cvtpk(peB[10], peB[11]);
      b0 = cvtpk(peB[12], peB[13]); b1 = cvtpk(peB[14], peB[15]);
      s0 = __builtin_amdgcn_permlane32_swap(a0, b0, false, false);
      s1 = __builtin_amdgcn_permlane32_swap(a1, b1, false, false);
      u32x4 w3 = {s0[0], s1[0], s0[1], s1[1]};
      pfvB[1] = __builtin_bit_cast(bf16x8, w3);
    }

    // V^T frags for next iter's PV (shared across both qsubs)
    {
      const bf16* vtb = &Vt[cur * 2048];
#pragma unroll
      for (int ks = 0; ks < 2; ks++) {
        const int off = (((ks * 2 + hi) ^ sw3) << 3);
        vf0[ks] = *(const bf16x8*)(vtb + baseV + off);
        vf1[ks] = *(const bf16x8*)(vtb + 1024 + baseV + off);
      }
    }

    __syncthreads();  // all waves done with cur buffers; drains prefetch vmcnt
  };

  body(t0, PvOff{});
  for (int kt = t0 + 1; kt < tend; kt++) body(kt, PvOn{});

  // epilogue PV for the last tile
  __builtin_amdgcn_s_setprio(1);
#pragma unroll
  for (int ks = 0; ks < 2; ks++) {
    o0 = MFMA32(vf0[ks], pfvA[ks], o0);
    o1 = MFMA32(vf1[ks], pfvA[ks], o1);
    o2 = MFMA32(vf0[ks], pfvB[ks], o2);
    o3 = MFMA32(vf1[ks], pfvB[ks], o3);
  }
  __builtin_amdgcn_s_setprio(0);

  // in-block combine, 4 phases of <=17 fields (17KB <= 32KB LDS)
  float* comb = (float*)smem;
  const int cbase = qw * 64 + lane;
  if (half) {
#pragma unroll
    for (int j = 0; j < 16; j++) comb[j * 256 + cbase] = o0[j];
    comb[16 * 256 + cbase] = lA;
  }
  __syncthreads();
  if (!half) {
#pragma unroll
    for (int j = 0; j < 16; j++) o0[j] += comb[j * 256 + cbase];
    lA += comb[16 * 256 + cbase];
  }
  __syncthreads();
  if (half) {
#pragma unroll
    for (int j = 0; j < 16; j++) comb[j * 256 + cbase] = o1[j];
  }
  __syncthreads();
  if (!half) {
#pragma unroll
    for (int j = 0; j < 16; j++) o1[j] += comb[j * 256 + cbase];
  }
  __syncthreads();
  if (half) {
#pragma unroll
    for (int j = 0; j < 16; j++) comb[j * 256 + cbase] = o2[j];
    comb[16 * 256 + cbase] = lB;
  }
  __syncthreads();
  if (!half) {
#pragma unroll
    for (int j = 0; j < 16; j++) o2[j] += comb[j * 256 + cbase];
    lB += comb[16 * 256 + cbase];
  }
  __syncthreads();
  if (half) {
#pragma unroll
    for (int j = 0; j < 16; j++) comb[j * 256 + cbase] = o3[j];
  }
  __syncthreads();
  if (!half) {
#pragma unroll
    for (int j = 0; j < 16; j++) o3[j] += comb[j * 256 + cbase];

    const int b = bh >> 4, h = bh & 15;
    float la = lA + __shfl_xor(lA, 32);
    float lb = lB + __shfl_xor(lB, 32);
    float invA = 1.0f / la;
    float invB = 1.0f / lb;
#pragma unroll
    for (int qs = 0; qs < 2; qs++) {
      const float inv = qs ? invB : invA;
      const int q = q0 + qw * 64 + qs * 32 + l31;
      bf16* orow = AO + (size_t)(b * Tn + q) * Cn + h * Dn;
#pragma unroll
      for (int dt = 0; dt < 2; dt++) {
        const f32x16& oo = qs ? (dt ? o3 : o2) : (dt ? o1 : o0);
#pragma unroll
        for (int rq = 0; rq < 4; rq++) {
          bf16x4 ov = {(bf16)(oo[rq * 4 + 0] * inv), (bf16)(oo[rq * 4 + 1] * inv),
                       (bf16)(oo[rq * 4 + 2] * inv), (bf16)(oo[rq * 4 + 3] * inv)};
          *(bf16x4*)&orow[dt * 32 + rq * 8 + hi * 4] = ov;
        }
      }
    }
  }
}

extern "C" void kernel_launch(void* const* d_in, const int* in_sizes, int n_in,
                              void* d_out, int out_size, void* d_ws, size_t ws_size,
                              hipStream_t stream) {
  const float* query = (const float*)d_in[0];
  const float* key   = (const float*)d_in[1];
  const float* value = (const float*)d_in[2];
  const float* Wq = (const float*)d_in[3];
  const float* bq = (const float*)d_in[4];
  const float* Wk = (const float*)d_in[5];
  const float* bk = (const float*)d_in[6];
  const float* Wv = (const float*)d_in[7];
  const float* bv = (const float*)d_in[8];
  const float* Wo = (const float*)d_in[9];
  const float* bo = (const float*)d_in[10];

  bf16* p = (bf16*)d_ws;
  bf16* WqT = p; p += WSZ;
  bf16* WkT = p; p += WSZ;
  bf16* WvT = p; p += WSZ;
  bf16* WoT = p; p += WSZ;
  bf16* Xbf = p; p += 3 * XSZ;   // bf16 activations; reused as AO after QKV GEMM
  bf16* Qh = p; p += XSZ;
  bf16* Kh = p; p += XSZ;
  bf16* VhT = p; p += XSZ;
  bf16* AO = Xbf;

  PrepArgs pa;
  pa.W[0] = Wq; pa.W[1] = Wk; pa.W[2] = Wv; pa.W[3] = Wo;
  pa.Wt[0] = WqT; pa.Wt[1] = WkT; pa.Wt[2] = WvT; pa.Wt[3] = WoT;
  pa.src[0] = query; pa.src[1] = key; pa.src[2] = value;
  pa.dst = Xbf;
  prep_kernel<<<dim3(6144 + 4096), 256, 0, stream>>>(pa);

  GemmArgs ga;
  ga.A[0] = Xbf; ga.A[1] = Xbf + XSZ; ga.A[2] = Xbf + 2 * XSZ;
  ga.Bt[0] = WqT;  ga.Bt[1] = WkT; ga.Bt[2] = WvT;
  ga.bias[0] = bq; ga.bias[1] = bk; ga.bias[2] = bv;
  ga.out[0] = Qh;  ga.out[1] = Kh;  ga.out[2] = VhT;
  ga.scale[0] = 0.125f * LOG2E; ga.scale[1] = 1.0f; ga.scale[2] = 1.0f;
  ga.layout[0] = 1; ga.layout[1] = 1; ga.layout[2] = 2;
  gemm_kernel<64><<<dim3(Cn / 128, Mn / 64, 3), 256, 0, stream>>>(ga, Cn);

  attn_kernel<<<dim3(256), 512, 0, stream>>>(Qh, Kh, VhT, AO);

  GemmArgs gb;
  gb.A[0] = AO; gb.Bt[0] = WoT; gb.bias[0] = bo; gb.out[0] = d_out; gb.scale[0] = 1.0f;
  gb.layout[0] = 0;
  gb.A[1] = gb.A[2] = nullptr; gb.Bt[1] = gb.Bt[2] = nullptr;
  gb.bias[1] = gb.bias[2] = nullptr; gb.out[1] = gb.out[2] = nullptr;
  gb.scale[1] = gb.scale[2] = 1.0f; gb.layout[1] = gb.layout[2] = 0;
  gemm_kernel<64><<<dim3(Cn / 128, Mn / 64, 1), 256, 0, stream>>>(gb, Cn);
}